// Round 1
// baseline (180.794 us; speedup 1.0000x reference)
//
#include <hip/hip_runtime.h>
#include <hip/hip_bf16.h>

// SparseAttentionHead on MI355X.
// out[i,c] = elu( sum_j P[i,j] * F[j,c] / Z[i] ),
//   P[i,j] = exp( adj[i,j] * lrelu(a1[i]+a2[j]) )   (adj in {0,1}; exp(0)=1 for adj=0)
//   Z[i]   = sum_j P[i,j]
// No max-subtraction needed: |a1+a2| <= ~10 -> exp safe in fp32.

typedef short bf16x8 __attribute__((ext_vector_type(8)));
typedef float f32x4 __attribute__((ext_vector_type(4)));

static __device__ __forceinline__ short f2bf(float f) {
  union { float f; unsigned u; } v; v.f = f;
  unsigned r = v.u + 0x7fffu + ((v.u >> 16) & 1u);
  return (short)(r >> 16);
}

// K1: seq_fts = W1 @ x  (fp32), store FT[c][n] = bf16(seq_fts), accumulate a1/a2.
// grid 256 = 8 cblocks x 32 nblocks, block 256 threads (one node per thread).
__global__ __launch_bounds__(256) void k1_seqfts(
    const float* __restrict__ x, const float* __restrict__ W1,
    const float* __restrict__ wf1, const float* __restrict__ wf2,
    short* __restrict__ FT, float* __restrict__ a1, float* __restrict__ a2) {
  const int cb = blockIdx.x & 7;
  const int nb = blockIdx.x >> 3;
  const int n = nb * 256 + threadIdx.x;
  float acc[16];
#pragma unroll
  for (int i = 0; i < 16; ++i) acc[i] = 0.f;
  const float* wrow = W1 + cb * 16 * 128;
#pragma unroll 4
  for (int c = 0; c < 128; ++c) {
    float xv = x[c * 8192 + n];
#pragma unroll
    for (int cc = 0; cc < 16; ++cc) acc[cc] = fmaf(wrow[cc * 128 + c], xv, acc[cc]);
  }
  float p1 = 0.f, p2 = 0.f;
#pragma unroll
  for (int cc = 0; cc < 16; ++cc) {
    int co = cb * 16 + cc;
    FT[co * 8192 + n] = f2bf(acc[cc]);
    p1 = fmaf(wf1[co], acc[cc], p1);
    p2 = fmaf(wf2[co], acc[cc], p2);
  }
  atomicAdd(&a1[n], p1);
  atomicAdd(&a2[n], p2);
}

// K2: one block per 32-row tile (grid 256, 512 threads = 8 waves).
// Sweep j in steps of 64: build P tile in LDS (bf16), MFMA against FT, track Z.
// Fused epilogue: out = elu(acc / Z).
__global__ __launch_bounds__(512, 2) void k2_attn(
    const float* __restrict__ adj, const short* __restrict__ FT,
    const float* __restrict__ a1, const float* __restrict__ a2,
    const float* __restrict__ b1p, const float* __restrict__ b2p,
    float* __restrict__ out) {
  __shared__ short Plds[32][88];   // pad to 88 (176B rows: 16B-aligned, low bank conflict)
  __shared__ float Zs[32];
  const int t = threadIdx.x;
  const int l = t & 63;
  const int w = t >> 6;          // wave 0..7 -> output cols 16w..16w+15
  const int row = t >> 4;        // P-producer row 0..31
  const int cg = t & 15;         // P-producer col group (4 floats)
  const int i0 = blockIdx.x * 32;
  const float af = a1[i0 + row] + b1p[0] + b2p[0];
  const float4* adjrow = (const float4*)(adj + (size_t)(i0 + row) * 8192) + cg;
  const float4* a2row = (const float4*)a2 + cg;
  const int arow = l & 15;       // MFMA fragment row/col within 16
  const int kg = l >> 4;         // k-group (8 contiguous k elems)
  const bf16x8* bp = (const bf16x8*)(FT + (size_t)(16 * w + arow) * 8192) + kg;
  const bf16x8* ap = (const bf16x8*)Plds;     // row stride = 88/8 = 11 units
  short* pw = &Plds[row][cg * 4];
  f32x4 acc0 = {0.f, 0.f, 0.f, 0.f};
  f32x4 acc1 = {0.f, 0.f, 0.f, 0.f};
  float zacc = 0.f;

  auto do_step = [&](int s, const float4 av, const float4 a2v) {
    float tt, lr, p0, p1, p2, p3;
    tt = af + a2v.x; lr = fmaxf(tt, 0.01f * tt); p0 = __expf(av.x * lr);
    tt = af + a2v.y; lr = fmaxf(tt, 0.01f * tt); p1 = __expf(av.y * lr);
    tt = af + a2v.z; lr = fmaxf(tt, 0.01f * tt); p2 = __expf(av.z * lr);
    tt = af + a2v.w; lr = fmaxf(tt, 0.01f * tt); p3 = __expf(av.w * lr);
    zacc += (p0 + p1) + (p2 + p3);
    ushort4 pb;
    pb.x = (unsigned short)f2bf(p0);
    pb.y = (unsigned short)f2bf(p1);
    pb.z = (unsigned short)f2bf(p2);
    pb.w = (unsigned short)f2bf(p3);
    *(ushort4*)pw = pb;
    __syncthreads();
    bf16x8 b0 = bp[s * 8];           // k = s*64 + kg*8
    bf16x8 b1 = bp[s * 8 + 4];       // k = s*64 + 32 + kg*8
    bf16x8 a00 = ap[arow * 11 + kg];
    bf16x8 a01 = ap[(16 + arow) * 11 + kg];
    bf16x8 a10 = ap[arow * 11 + 4 + kg];
    bf16x8 a11 = ap[(16 + arow) * 11 + 4 + kg];
    acc0 = __builtin_amdgcn_mfma_f32_16x16x32_bf16(a00, b0, acc0, 0, 0, 0);
    acc1 = __builtin_amdgcn_mfma_f32_16x16x32_bf16(a01, b0, acc1, 0, 0, 0);
    acc0 = __builtin_amdgcn_mfma_f32_16x16x32_bf16(a10, b1, acc0, 0, 0, 0);
    acc1 = __builtin_amdgcn_mfma_f32_16x16x32_bf16(a11, b1, acc1, 0, 0, 0);
    __syncthreads();
  };

  // 2-deep register prefetch of adj + a2 (named buffers: no runtime indexing).
  float4 adjA = adjrow[0], a2A = a2row[0];
  float4 adjB = adjrow[16], a2B = a2row[16];
  for (int s = 0; s < 128; s += 2) {
    float4 cA = adjA, c2A = a2A;
    if (s + 2 < 128) { adjA = adjrow[(s + 2) * 16]; a2A = a2row[(s + 2) * 16]; }
    do_step(s, cA, c2A);
    float4 cB = adjB, c2B = a2B;
    if (s + 3 < 128) { adjB = adjrow[(s + 3) * 16]; a2B = a2row[(s + 3) * 16]; }
    do_step(s + 1, cB, c2B);
  }

  // Z: reduce across the 16 threads that share a row (contiguous 16-lane groups).
  float zr = zacc;
#pragma unroll
  for (int d = 8; d > 0; d >>= 1) zr += __shfl_down(zr, d, 16);
  if ((l & 15) == 0) Zs[w * 4 + kg] = zr;
  __syncthreads();

  // Epilogue: normalize + elu + store. C/D layout: col=l&15, row=4*(l>>4)+q.
#pragma unroll
  for (int rt = 0; rt < 2; ++rt) {
    f32x4 a = rt ? acc1 : acc0;
#pragma unroll
    for (int q = 0; q < 4; ++q) {
      int lrow = rt * 16 + 4 * kg + q;
      float v = a[q] / Zs[lrow];
      v = v > 0.f ? v : __expf(v) - 1.f;
      out[(size_t)(i0 + lrow) * 128 + 16 * w + arow] = v;
    }
  }
}

extern "C" void kernel_launch(void* const* d_in, const int* in_sizes, int n_in,
                              void* d_out, int out_size, void* d_ws, size_t ws_size,
                              hipStream_t stream) {
  const float* x   = (const float*)d_in[0];
  // d_in[1] = edge_index (unused by the reference computation)
  const float* adj = (const float*)d_in[2];
  const float* W1  = (const float*)d_in[3];
  const float* wf1 = (const float*)d_in[4];
  const float* b1  = (const float*)d_in[5];
  const float* wf2 = (const float*)d_in[6];
  const float* b2  = (const float*)d_in[7];
  float* out = (float*)d_out;

  short* FT = (short*)d_ws;                                   // 128*8192 bf16 = 2MB
  float* a1 = (float*)((char*)d_ws + (size_t)2 * 1024 * 1024); // 8192 f32
  float* a2 = a1 + 8192;                                       // 8192 f32

  hipMemsetAsync(a1, 0, 2 * 8192 * sizeof(float), stream);
  k1_seqfts<<<256, 256, 0, stream>>>(x, W1, wf1, wf2, FT, a1, a2);
  k2_attn<<<256, 512, 0, stream>>>(adj, FT, a1, a2, b1, b2, out);
}